// Round 1
// baseline (212.909 us; speedup 1.0000x reference)
//
#include <hip/hip_runtime.h>

// NCC loss, fully fused: products + separable 9^3 box sums + cc + mean, one pass.
// Input vols: [B=2][D=160][H=192][W=160] fp32. Output: scalar fp32 = -mean(cc).

#define B_   2
#define D_   160
#define H_   192
#define W_   160
#define TH   16            // output tile h
#define TW   16            // output tile w
#define SH   24            // TH + 8 halo
#define SW   24            // TW + 8 halo
#define SSTR 37            // stage row stride (floats), padded for bank spread
#define WSTR 17            // wsum/hsum row stride
#define DC   40            // d outputs per chunk (160/40 = 4 chunks)
#define NSTEP (DC + 8)     // slices streamed per chunk
#define WIN3_INV (1.0f/729.0f)
#define NTOT 9830400.0f    // 2*160*192*160

__global__ __launch_bounds__(256) void ncc_fused(
    const float* __restrict__ I, const float* __restrict__ J,
    float* __restrict__ out)
{
  const int tid  = threadIdx.x;
  const int w0   = blockIdx.x * TW;
  const int h0   = blockIdx.y * TH;
  const int bz   = blockIdx.z;
  const int bb   = bz >> 2;            // batch
  const int d_lo = (bz & 3) * DC;      // chunk start

  __shared__ float sI[SH*SSTR];
  __shared__ float sJ[SH*SSTR];
  __shared__ float wsum[5*SH*WSTR];    // w-summed, rows = h-halo (24), cols = 16
  __shared__ float hsum[5*TH*WSTR];    // w+h summed, 16x16 per field
  __shared__ float red[4];

  // per-output-column d-window state: 9-deep ring + running sums, 5 fields
  float ring[5][9];
  float S[5];
  #pragma unroll
  for (int f = 0; f < 5; ++f) {
    S[f] = 0.f;
    #pragma unroll
    for (int k = 0; k < 9; ++k) ring[f][k] = 0.f;
  }
  float acc = 0.f;

  // stage-role indices
  const int wr  = tid >> 3;    // w-stage: row 0..23 (tid<192)
  const int wp  = tid & 7;     // w-stage: output pair 0..7
  const int hwi = tid & 15;    // h-stage: w index
  const int hf  = (tid >> 4) % 5;   // h-stage: field
  const int hph = tid / 80;    // h-stage: half 0/1 (tid<160)
  const int rw  = tid & 15;    // ring stage: w
  const int rh  = tid >> 4;    // ring stage: h

  for (int step = 0; step < NSTEP; ++step) {
    const int s = d_lo - 4 + step;
    const bool sin_d = (unsigned)s < (unsigned)D_;

    // ---- stage raw I,J slice tile into LDS (zero OOB = 'same' zero pad) ----
    for (int i = tid; i < SH*SW; i += 256) {
      const int r = i / SW, c = i - r*SW;
      const int gh = h0 - 4 + r, gw = w0 - 4 + c;
      float vi = 0.f, vj = 0.f;
      if (sin_d && (unsigned)gh < (unsigned)H_ && (unsigned)gw < (unsigned)W_) {
        const size_t off = ((size_t)(bb*D_ + s)*H_ + gh)*W_ + gw;
        vi = I[off]; vj = J[off];
      }
      sI[r*SSTR + c] = vi;
      sJ[r*SSTR + c] = vj;
    }
    __syncthreads();

    // ---- w-window sums (run of 2 outputs/thread, 5 fields on the fly) ----
    if (tid < 192) {
      float s0[5] = {0,0,0,0,0}, s1[5] = {0,0,0,0,0};
      const int base = wr*SSTR + 2*wp;
      #pragma unroll
      for (int k = 0; k < 10; ++k) {
        const float iv = sI[base + k];
        const float jv = sJ[base + k];
        const float p2 = iv*iv, p3 = jv*jv, p4 = iv*jv;
        if (k < 9) { s0[0]+=iv; s0[1]+=jv; s0[2]+=p2; s0[3]+=p3; s0[4]+=p4; }
        if (k > 0) { s1[0]+=iv; s1[1]+=jv; s1[2]+=p2; s1[3]+=p3; s1[4]+=p4; }
      }
      const int ob = wr*WSTR + 2*wp;
      #pragma unroll
      for (int f = 0; f < 5; ++f) {
        wsum[f*(SH*WSTR) + ob]     = s0[f];
        wsum[f*(SH*WSTR) + ob + 1] = s1[f];
      }
    }
    __syncthreads();

    // ---- h-window sums (run of 8 outputs/thread, one field each) ----
    if (tid < 160) {
      float v[16];
      const int fb = hf*(SH*WSTR) + hwi;
      #pragma unroll
      for (int k = 0; k < 16; ++k) v[k] = wsum[fb + (8*hph + k)*WSTR];
      float sum = 0.f;
      #pragma unroll
      for (int k = 0; k < 9; ++k) sum += v[k];
      const int hb = hf*(TH*WSTR) + hwi;
      hsum[hb + (8*hph)*WSTR] = sum;
      #pragma unroll
      for (int k = 1; k < 8; ++k) {
        sum += v[k+8] - v[k-1];
        hsum[hb + (8*hph + k)*WSTR] = sum;
      }
    }
    __syncthreads();

    // ---- d ring update + cc (every thread owns one (h,w) column) ----
    {
      float nv[5];
      #pragma unroll
      for (int f = 0; f < 5; ++f)
        nv[f] = hsum[f*(TH*WSTR) + rh*WSTR + rw];
      #pragma unroll
      for (int f = 0; f < 5; ++f) {
        S[f] += nv[f] - ring[f][8];
        #pragma unroll
        for (int k = 8; k > 0; --k) ring[f][k] = ring[f][k-1];
        ring[f][0] = nv[f];
      }
      if (step >= 8) {  // output slice d = s-4 is in [d_lo, d_lo+DC)
        const float si = S[0], sj = S[1], si2 = S[2], sj2 = S[3], sij = S[4];
        const float cross = sij - si*sj*WIN3_INV;
        const float iv    = si2 - si*si*WIN3_INV;
        const float jv    = sj2 - sj*sj*WIN3_INV;
        acc += cross*cross / (iv*jv + 1e-5f);
      }
    }
    // next iter's staging writes sI/sJ; ordered vs this iter's reads by the
    // syncthreads above (wsum/hsum buffers are distinct from sI/sJ).
  }

  // ---- block reduction -> single atomic ----
  float v = acc;
  #pragma unroll
  for (int off = 32; off > 0; off >>= 1)
    v += __shfl_down(v, off, 64);
  if ((tid & 63) == 0) red[tid >> 6] = v;
  __syncthreads();
  if (tid == 0) {
    const float t = red[0] + red[1] + red[2] + red[3];
    atomicAdd(out, -t / NTOT);
  }
}

extern "C" void kernel_launch(void* const* d_in, const int* in_sizes, int n_in,
                              void* d_out, int out_size, void* d_ws, size_t ws_size,
                              hipStream_t stream) {
  const float* J = (const float*)d_in[0];  // y_pred
  const float* I = (const float*)d_in[1];  // y_true (cc is symmetric in I,J)
  float* out = (float*)d_out;
  hipMemsetAsync(d_out, 0, sizeof(float), stream);
  dim3 grid(W_/TW, H_/TH, B_*4);   // 10 x 12 x 8 = 960 blocks
  ncc_fused<<<grid, dim3(256), 0, stream>>>(I, J, out);
}